// Round 4
// baseline (549.449 us; speedup 1.0000x reference)
//
#include <hip/hip_runtime.h>

#define OUT_W 7
#define OUT_L 7
#define OUT_H 7
#define SR 2
#define CDIM 128
#define WDIM 64
#define LDIM 64
#define HDIM 64
#define VOLSZ (WDIM * LDIM * HDIM)
#define CPB 4  // channels per block

// b00..b11: flat (x,y) column base offsets for the 4 xy corners of a sample.
struct ColInfo { int b00, b10, b01, b11; float w00, w10, w01, w11; };

// One block per (n, channel-quad). Threads = output bins (343 active of 384).
// Per-bin z work (2 sub-samples x 2 taps) folds into an 8-tap z filter over
// two aligned float4 loads (all 4 z taps span <=5 voxels; z-step <= 2.29).
// Loads are issued in batches of 16 float4 (2 channels x 4 corners x 2) to
// maximize memory-level parallelism -- we are latency-bound, not BW-bound.
__global__ __launch_bounds__(384) void roi_align_rot3d_kernel(
    const float* __restrict__ input, const float* __restrict__ rois,
    const float* __restrict__ scale_ptr, float* __restrict__ out)
{
    __shared__ ColInfo cols[OUT_W * SR * OUT_L * SR];   // 196 * 32B
    __shared__ alignas(16) float zw[OUT_H][8];          // 7 x 8 z-weights (per bin)
    __shared__ int zb4s[OUT_H];                         // 7 aligned bases

    const int n = blockIdx.x / (CDIM / CPB);
    const int cp = blockIdx.x - n * (CDIM / CPB);
    const int c0 = cp * CPB;
    const int t = threadIdx.x;

    const float scale = scale_ptr[0];
    const float* r = rois + (size_t)n * 8;
    const int   b  = (int)r[0];
    const float cx = r[1] * scale, cy = r[2] * scale, cz = r[3] * scale;
    const float sx = r[4] * scale, sy = r[5] * scale, szv = r[6] * scale;
    const float th = r[7];
    const float ct = cosf(th), st = sinf(th);

    if (t < 196) {
        const int isx = t / 14, isy = t - isx * 14;
        const float xx = -0.5f * sx + ((float)isx + 0.5f) * (sx * (1.0f / 14.0f));
        const float yy = -0.5f * sy + ((float)isy + 0.5f) * (sy * (1.0f / 14.0f));
        float x = ct * xx - st * yy + cx;
        float y = st * xx + ct * yy + cy;
        const bool v = (x > -1.0f) && (x < (float)WDIM) && (y > -1.0f) && (y < (float)LDIM);
        x = fminf(fmaxf(x, 0.0f), (float)(WDIM - 1));
        y = fminf(fmaxf(y, 0.0f), (float)(LDIM - 1));
        const int x0 = (int)floorf(x);
        const int y0 = (int)floorf(y);
        const int x1 = min(x0 + 1, WDIM - 1);
        const int y1 = min(y0 + 1, LDIM - 1);
        const float lx = x - (float)x0, ly = y - (float)y0;
        const float hx = 1.0f - lx, hy = 1.0f - ly;
        const float vm = v ? 1.0f : 0.0f;
        cols[t].b00 = x0 * (LDIM * HDIM) + y0 * HDIM;
        cols[t].b10 = x1 * (LDIM * HDIM) + y0 * HDIM;
        cols[t].b01 = x0 * (LDIM * HDIM) + y1 * HDIM;
        cols[t].b11 = x1 * (LDIM * HDIM) + y1 * HDIM;
        cols[t].w00 = hx * hy * vm; cols[t].w10 = lx * hy * vm;
        cols[t].w01 = hx * ly * vm; cols[t].w11 = lx * ly * vm;
    } else if (t < 196 + OUT_H) {     // one thread per output z-bin
        const int oh = t - 196;
        float w[8];
        #pragma unroll
        for (int k = 0; k < 8; ++k) w[k] = 0.0f;
        int zb4 = 0;
        #pragma unroll
        for (int dz = 0; dz < 2; ++dz) {
            const int s = oh * 2 + dz;
            const float zraw = -0.5f * szv + ((float)s + 0.5f) * (szv * (1.0f / 14.0f)) + cz;
            const bool v = (zraw > -1.0f) && (zraw < (float)HDIM);
            const float z = fminf(fmaxf(zraw, 0.0f), (float)(HDIM - 1));
            const int z0 = (int)floorf(z);
            const int z1 = min(z0 + 1, HDIM - 1);
            const float lz = z - (float)z0, hz = 1.0f - lz;
            const float vm = v ? 1.0f : 0.0f;
            if (dz == 0) zb4 = min(z0 & ~3, HDIM - 8);
            w[z0 - zb4] += hz * vm;
            w[z1 - zb4] += lz * vm;
        }
        zb4s[oh] = zb4;
        #pragma unroll
        for (int k = 0; k < 8; ++k) zw[oh][k] = w[k];
    }
    __syncthreads();

    if (t >= 343) return;
    const int ow = t / 49;
    const int rem = t - ow * 49;
    const int ol = rem / 7;
    const int oh = rem - ol * 7;

    const float4 zwa = *(const float4*)&zw[oh][0];
    const float4 zwb = *(const float4*)&zw[oh][4];
    const int zb4 = zb4s[oh];

    const float* __restrict__ p =
        input + ((size_t)(b * CDIM + c0)) * (size_t)VOLSZ;

    float acc[CPB];
    #pragma unroll
    for (int cc = 0; cc < CPB; ++cc) acc[cc] = 0.0f;

    #pragma unroll
    for (int dx = 0; dx < 2; ++dx) {
        #pragma unroll
        for (int dy = 0; dy < 2; ++dy) {
            const ColInfo col = cols[(ow * 2 + dx) * 14 + (ol * 2 + dy)];
            const int ofs[4] = { col.b00 + zb4, col.b10 + zb4,
                                 col.b01 + zb4, col.b11 + zb4 };
            const float cw[4] = { col.w00, col.w10, col.w01, col.w11 };
            // process channels in pairs: issue 16 float4 loads, then reduce
            #pragma unroll
            for (int cp2 = 0; cp2 < CPB / 2; ++cp2) {
                float4 va[2][4], vb[2][4];
                #pragma unroll
                for (int j = 0; j < 2; ++j) {
                    const float* __restrict__ pc = p + (size_t)(cp2 * 2 + j) * VOLSZ;
                    #pragma unroll
                    for (int k = 0; k < 4; ++k) {
                        va[j][k] = *(const float4*)(pc + ofs[k]);
                        vb[j][k] = *(const float4*)(pc + ofs[k] + 4);
                    }
                }
                #pragma unroll
                for (int j = 0; j < 2; ++j) {
                    float s = 0.0f;
                    #pragma unroll
                    for (int k = 0; k < 4; ++k) {
                        const float4 a = va[j][k], bv = vb[j][k];
                        const float v = zwa.x * a.x + zwa.y * a.y + zwa.z * a.z + zwa.w * a.w
                                      + zwb.x * bv.x + zwb.y * bv.y + zwb.z * bv.z + zwb.w * bv.w;
                        s += cw[k] * v;
                    }
                    acc[cp2 * 2 + j] += s;
                }
            }
        }
    }
    #pragma unroll
    for (int cc = 0; cc < CPB; ++cc) {
        out[((size_t)(n * CDIM + c0 + cc)) * 343 + t] = acc[cc] * 0.125f;
    }
}

extern "C" void kernel_launch(void* const* d_in, const int* in_sizes, int n_in,
                              void* d_out, int out_size, void* d_ws, size_t ws_size,
                              hipStream_t stream) {
    const float* input = (const float*)d_in[0];
    const float* rois  = (const float*)d_in[1];
    const float* scale = (const float*)d_in[2];
    float* out = (float*)d_out;
    const int N = in_sizes[1] / 8;
    dim3 grid((unsigned)(N * (CDIM / CPB)));
    dim3 block(384);
    hipLaunchKernelGGL(roi_align_rot3d_kernel, grid, block, 0, stream,
                       input, rois, scale, out);
}

// Round 5
// 485.664 us; speedup vs baseline: 1.1313x; 1.1313x over previous
//
#include <hip/hip_runtime.h>

#define OUT_W 7
#define OUT_L 7
#define OUT_H 7
#define SR 2
#define CDIM 128
#define WDIM 64
#define LDIM 64
#define HDIM 64
#define VOLSZ (WDIM * LDIM * HDIM)
#define CPB 2  // channels per block (traffic-optimal per R3/R4 A/B)

typedef float f4 __attribute__((ext_vector_type(4)));

// Compiler-proof deep load batch: volatile asm loads stay issued back-to-back;
// results only become usable through the s_waitcnt asm that ties all 16 regs.
#define GLOAD(dst, p) asm volatile("global_load_dwordx4 %0, %1, off" : "=v"(dst) : "v"(p))

struct ColInfo { int b00, b10, b01, b11; float w00, w10, w01, w11; };

// One block per (n, channel-pair). Threads = output bins (343 active of 384).
// Per-bin z work (2 sub-samples x 2 taps) folds into an 8-tap z filter over
// two aligned float4 loads (all 4 z taps span <=5 voxels; z-step <= 2.29).
// 16 float4 loads (2 ch x 4 xy-corners x 2 halves) are forced in-flight per
// (dx,dy) step via inline asm -- we are MLP/latency-bound, not BW-bound.
__global__ __launch_bounds__(384) void roi_align_rot3d_kernel(
    const float* __restrict__ input, const float* __restrict__ rois,
    const float* __restrict__ scale_ptr, float* __restrict__ out)
{
    __shared__ ColInfo cols[OUT_W * SR * OUT_L * SR];   // 196 * 32B
    __shared__ alignas(16) float zw[OUT_H][8];          // 7 x 8 z-weights (per bin)
    __shared__ int zb4s[OUT_H];                         // 7 aligned bases

    const int n = blockIdx.x / (CDIM / CPB);
    const int cp = blockIdx.x - n * (CDIM / CPB);
    const int c0 = cp * CPB;
    const int t = threadIdx.x;

    const float scale = scale_ptr[0];
    const float* r = rois + (size_t)n * 8;
    const int   b  = (int)r[0];
    const float cx = r[1] * scale, cy = r[2] * scale, cz = r[3] * scale;
    const float sx = r[4] * scale, sy = r[5] * scale, szv = r[6] * scale;
    const float th = r[7];
    const float ct = cosf(th), st = sinf(th);

    if (t < 196) {
        const int isx = t / 14, isy = t - isx * 14;
        const float xx = -0.5f * sx + ((float)isx + 0.5f) * (sx * (1.0f / 14.0f));
        const float yy = -0.5f * sy + ((float)isy + 0.5f) * (sy * (1.0f / 14.0f));
        float x = ct * xx - st * yy + cx;
        float y = st * xx + ct * yy + cy;
        const bool v = (x > -1.0f) && (x < (float)WDIM) && (y > -1.0f) && (y < (float)LDIM);
        x = fminf(fmaxf(x, 0.0f), (float)(WDIM - 1));
        y = fminf(fmaxf(y, 0.0f), (float)(LDIM - 1));
        const int x0 = (int)floorf(x);
        const int y0 = (int)floorf(y);
        const int x1 = min(x0 + 1, WDIM - 1);
        const int y1 = min(y0 + 1, LDIM - 1);
        const float lx = x - (float)x0, ly = y - (float)y0;
        const float hx = 1.0f - lx, hy = 1.0f - ly;
        const float vm = v ? 1.0f : 0.0f;
        cols[t].b00 = x0 * (LDIM * HDIM) + y0 * HDIM;
        cols[t].b10 = x1 * (LDIM * HDIM) + y0 * HDIM;
        cols[t].b01 = x0 * (LDIM * HDIM) + y1 * HDIM;
        cols[t].b11 = x1 * (LDIM * HDIM) + y1 * HDIM;
        cols[t].w00 = hx * hy * vm; cols[t].w10 = lx * hy * vm;
        cols[t].w01 = hx * ly * vm; cols[t].w11 = lx * ly * vm;
    } else if (t < 196 + OUT_H) {     // one thread per output z-bin
        const int oh = t - 196;
        float w[8];
        #pragma unroll
        for (int k = 0; k < 8; ++k) w[k] = 0.0f;
        int zb4 = 0;
        #pragma unroll
        for (int dz = 0; dz < 2; ++dz) {
            const int s = oh * 2 + dz;
            const float zraw = -0.5f * szv + ((float)s + 0.5f) * (szv * (1.0f / 14.0f)) + cz;
            const bool v = (zraw > -1.0f) && (zraw < (float)HDIM);
            const float z = fminf(fmaxf(zraw, 0.0f), (float)(HDIM - 1));
            const int z0 = (int)floorf(z);
            const int z1 = min(z0 + 1, HDIM - 1);
            const float lz = z - (float)z0, hz = 1.0f - lz;
            const float vm = v ? 1.0f : 0.0f;
            if (dz == 0) zb4 = min(z0 & ~3, HDIM - 8);
            w[z0 - zb4] += hz * vm;
            w[z1 - zb4] += lz * vm;
        }
        zb4s[oh] = zb4;
        #pragma unroll
        for (int k = 0; k < 8; ++k) zw[oh][k] = w[k];
    }
    __syncthreads();

    if (t >= 343) return;
    const int ow = t / 49;
    const int rem = t - ow * 49;
    const int ol = rem / 7;
    const int oh = rem - ol * 7;

    const float4 zwa = *(const float4*)&zw[oh][0];
    const float4 zwb = *(const float4*)&zw[oh][4];
    const int zb4 = zb4s[oh];

    const float* __restrict__ p =
        input + ((size_t)(b * CDIM + c0)) * (size_t)VOLSZ;

    float acc0 = 0.0f, acc1 = 0.0f;

    #pragma unroll
    for (int dx = 0; dx < 2; ++dx) {
        #pragma unroll
        for (int dy = 0; dy < 2; ++dy) {
            const ColInfo col = cols[(ow * 2 + dx) * 14 + (ol * 2 + dy)];
            const float* a0 = p + (col.b00 + zb4);
            const float* a1 = p + (col.b10 + zb4);
            const float* a2 = p + (col.b01 + zb4);
            const float* a3 = p + (col.b11 + zb4);
            const float* b0 = a0 + VOLSZ;
            const float* b1 = a1 + VOLSZ;
            const float* b2 = a2 + VOLSZ;
            const float* b3 = a3 + VOLSZ;
            f4 r00, r01, r02, r03, r04, r05, r06, r07;
            f4 r08, r09, r10, r11, r12, r13, r14, r15;
            GLOAD(r00, a0); GLOAD(r01, a0 + 4);
            GLOAD(r02, a1); GLOAD(r03, a1 + 4);
            GLOAD(r04, a2); GLOAD(r05, a2 + 4);
            GLOAD(r06, a3); GLOAD(r07, a3 + 4);
            GLOAD(r08, b0); GLOAD(r09, b0 + 4);
            GLOAD(r10, b1); GLOAD(r11, b1 + 4);
            GLOAD(r12, b2); GLOAD(r13, b2 + 4);
            GLOAD(r14, b3); GLOAD(r15, b3 + 4);
            asm volatile("s_waitcnt vmcnt(0)"
                : "+v"(r00), "+v"(r01), "+v"(r02), "+v"(r03),
                  "+v"(r04), "+v"(r05), "+v"(r06), "+v"(r07),
                  "+v"(r08), "+v"(r09), "+v"(r10), "+v"(r11),
                  "+v"(r12), "+v"(r13), "+v"(r14), "+v"(r15));
            const float v00 = zwa.x*r00.x + zwa.y*r00.y + zwa.z*r00.z + zwa.w*r00.w
                            + zwb.x*r01.x + zwb.y*r01.y + zwb.z*r01.z + zwb.w*r01.w;
            const float v10 = zwa.x*r02.x + zwa.y*r02.y + zwa.z*r02.z + zwa.w*r02.w
                            + zwb.x*r03.x + zwb.y*r03.y + zwb.z*r03.z + zwb.w*r03.w;
            const float v01 = zwa.x*r04.x + zwa.y*r04.y + zwa.z*r04.z + zwa.w*r04.w
                            + zwb.x*r05.x + zwb.y*r05.y + zwb.z*r05.z + zwb.w*r05.w;
            const float v11 = zwa.x*r06.x + zwa.y*r06.y + zwa.z*r06.z + zwa.w*r06.w
                            + zwb.x*r07.x + zwb.y*r07.y + zwb.z*r07.z + zwb.w*r07.w;
            acc0 += col.w00 * v00 + col.w10 * v10 + col.w01 * v01 + col.w11 * v11;
            const float u00 = zwa.x*r08.x + zwa.y*r08.y + zwa.z*r08.z + zwa.w*r08.w
                            + zwb.x*r09.x + zwb.y*r09.y + zwb.z*r09.z + zwb.w*r09.w;
            const float u10 = zwa.x*r10.x + zwa.y*r10.y + zwa.z*r10.z + zwa.w*r10.w
                            + zwb.x*r11.x + zwb.y*r11.y + zwb.z*r11.z + zwb.w*r11.w;
            const float u01 = zwa.x*r12.x + zwa.y*r12.y + zwa.z*r12.z + zwa.w*r12.w
                            + zwb.x*r13.x + zwb.y*r13.y + zwb.z*r13.z + zwb.w*r13.w;
            const float u11 = zwa.x*r14.x + zwa.y*r14.y + zwa.z*r14.z + zwa.w*r14.w
                            + zwb.x*r15.x + zwb.y*r15.y + zwb.z*r15.z + zwb.w*r15.w;
            acc1 += col.w00 * u00 + col.w10 * u10 + col.w01 * u01 + col.w11 * u11;
        }
    }
    out[((size_t)(n * CDIM + c0 + 0)) * 343 + t] = acc0 * 0.125f;
    out[((size_t)(n * CDIM + c0 + 1)) * 343 + t] = acc1 * 0.125f;
}

extern "C" void kernel_launch(void* const* d_in, const int* in_sizes, int n_in,
                              void* d_out, int out_size, void* d_ws, size_t ws_size,
                              hipStream_t stream) {
    const float* input = (const float*)d_in[0];
    const float* rois  = (const float*)d_in[1];
    const float* scale = (const float*)d_in[2];
    float* out = (float*)d_out;
    const int N = in_sizes[1] / 8;
    dim3 grid((unsigned)(N * (CDIM / CPB)));
    dim3 block(384);
    hipLaunchKernelGGL(roi_align_rot3d_kernel, grid, block, 0, stream,
                       input, rois, scale, out);
}